// Round 4
// baseline (272.086 us; speedup 1.0000x reference)
//
#include <hip/hip_runtime.h>
#include <cstdint>

static constexpr int S = 1024;
static constexpr int T = 32;
static constexpr float L2E  = 1.4426950408889634f;  // log2(e)
static constexpr float LN2f = 0.6931471805599453f;  // ln(2)

typedef __attribute__((ext_vector_type(8)))  short  short8;
typedef __attribute__((ext_vector_type(16))) float  float16;

union Frag { unsigned u[4]; short8 s; };

__global__ void crf_zero(float* ws) {
  ws[0] = 0.0f; ws[1] = 0.0f; ((unsigned*)ws)[2] = 0u;
}

__device__ __forceinline__ float bcast_lane(float v, int k) {
  return __uint_as_float((unsigned)__builtin_amdgcn_readlane((int)__float_as_uint(v), k));
}

// single-instruction rounded pack: two f32 -> bf16x2 (lo = first arg).
__device__ __forceinline__ unsigned cvtpk(float lo, float hi) {
  unsigned r;
  asm("v_cvt_pk_bf16_f32 %0, %1, %2" : "=v"(r) : "v"(lo), "v"(hi));
  return r;
}

// async global->LDS, 16 B per lane: dest = wave-uniform base + lane*16.
__device__ __forceinline__ void gload16(const float* src, float* dst) {
  __builtin_amdgcn_global_load_lds(
      (const __attribute__((address_space(1))) unsigned int*)(src),
      (__attribute__((address_space(3))) unsigned int*)(dst),
      16, 0, 0);
}

// sigma: fixed row permutation mapping MFMA C-layout row slots onto B-operand
// row slots (swaps 4-blocks 1<->2 within each 16). With A pre-permuted
// (A'[m][k] = X[m][sig(k)]) the product is exact and D's packed pairs ARE the
// next B-operand - no lane data movement. Note sig(16+k) = 16+sig(k).
__device__ __forceinline__ int sig(int k) {
  int g2 = (k >> 2) & 3;
  if (g2 == 1) g2 = 2; else if (g2 == 2) g2 = 1;
  return (k & ~12) | (g2 << 2);
}

// Block = one batch (512 thr = 8 waves). Active range (head, tail] split into
// 8 equal chunks. Each wave folds its chunk with TWO independent MFMA chains
// (ILP: chain latency hides under the other chain's VALU work):
//   chain 1 (forward, first half):  M1 <- diag(g_j) P^T M1   (B-frag state)
//   chain 2 (reverse, second half): N  <- P diag(g_j) N      (f32 C-layout
//     pending state), which builds N = M2^T processed j descending.
// Combine: by A/B layout symmetry, feeding N's B-format frags as the MFMA *A*
// operand multiplies by N^T = M2, so C = mfma(N, M1) = M2*M1 directly.
__global__ __launch_bounds__(512, 4) void crf_main(
    const float* __restrict__ em, const int* __restrict__ tags,
    const int* __restrict__ mask, const float* __restrict__ startT,
    const float* __restrict__ trans, const float* __restrict__ endT,
    float* __restrict__ ws, float* __restrict__ out, int B)
{
  __shared__ __align__(16) float    s_g32[8 * 1024];   // 32 KiB: per wave 2 chains x dbuf x (8 steps x 32 tags)
  __shared__ __align__(16) unsigned s_mats[8 * 544];   // 17 KiB: bf16 chunk mats, rows pad 34
  __shared__ float s_trans[1024];                      // 4 KiB
  __shared__ short s_tags[1024];                       // 2 KiB
  __shared__ unsigned long long s_mb[17];
  __shared__ int   s_head, s_tail, s_cnt, s_K[8];
  __shared__ float s_num[8];

  const int tid = threadIdx.x;
  const int l   = tid & 63;
  const int wv  = tid >> 6;
  const int b   = blockIdx.x;
  const int n   = l & 31;        // MFMA column / tag index
  const int h   = l >> 5;        // lane half

  const float* emb   = em   + (size_t)b * S * T;
  const int*   maskb = mask + (size_t)b * S;
  const int*   tagsb = tags + (size_t)b * S;

  // ---- cooperative staging: tags, trans, mask ballots ----
  for (int i = tid; i < 1024; i += 512) {
    s_tags[i]  = (short)tagsb[i];
    s_trans[i] = trans[i];
  }
  {
    unsigned long long b0 = __ballot(maskb[wv * 128 + l] != 0);
    unsigned long long b1 = __ballot(maskb[wv * 128 + 64 + l] != 0);
    if (l == 0) { s_mb[2 * wv] = b0; s_mb[2 * wv + 1] = b1; }
    if (tid == 0) s_mb[16] = 0ull;
  }

  // ---- A1 = sigma-permuted P^T (fwd chain), A2 = sigma-permuted P (rev) ----
  Frag A1lo, A1hi, A2lo, A2hi;
  #pragma unroll
  for (int p = 0; p < 4; ++p) {
    int k0 = 8 * h + 2 * p;
    A1lo.u[p] = cvtpk(exp2f(trans[sig(k0 + 0)      * T + n] * L2E),
                      exp2f(trans[sig(k0 + 1)      * T + n] * L2E));
    A1hi.u[p] = cvtpk(exp2f(trans[sig(16 + k0 + 0) * T + n] * L2E),
                      exp2f(trans[sig(16 + k0 + 1) * T + n] * L2E));
    A2lo.u[p] = cvtpk(exp2f(trans[n * T + sig(k0 + 0)] * L2E),
                      exp2f(trans[n * T + sig(k0 + 1)] * L2E));
    A2hi.u[p] = cvtpk(exp2f(trans[n * T + sig(16 + k0 + 0)] * L2E),
                      exp2f(trans[n * T + sig(16 + k0 + 1)] * L2E));
  }
  __syncthreads();

  if (wv == 0) {
    int first = 0x7fffffff, last = -1, pc = 0;
    if (l < 16) {
      unsigned long long w = s_mb[l];
      if (w) {
        first = 64 * l + (int)__builtin_ctzll(w);
        last  = 64 * l + 63 - (int)__builtin_clzll(w);
        pc    = (int)__builtin_popcountll(w);
      }
    }
    #pragma unroll
    for (int d = 1; d < 64; d <<= 1) {
      first = min(first, __shfl_xor(first, d));
      last  = max(last,  __shfl_xor(last,  d));
      pc   += __shfl_xor(pc, d);
    }
    if (l == 0) { s_head = first; s_tail = last; s_cnt = pc; }
  }
  __syncthreads();
  const int cnt  = s_cnt;
  const int head = (cnt > 0) ? s_head : 0;
  const int tail = (cnt > 0) ? s_tail : 0;

  // ---- equal-split chunk for this wave, halved across the two chains ----
  const int span = tail - head;
  const int Lc   = (span + 7) >> 3;
  const int c0   = head + 1 + wv * Lc;
  const int c1   = min(c0 + Lc, tail + 1);
  const int cm   = c0 + ((max(c1 - c0, 0) + 1) >> 1);   // len1 >= len2
  const int len1 = cm - c0;
  const int nw   = (len1 + 7) >> 3;

  float* w1 = s_g32 + wv * 1024;     // chain-1 dbuf windows (+0 / +256)
  float* w2 = w1 + 512;              // chain-2 dbuf windows (+0 / +256)

  Frag Blo, Bhi;                     // chain-1 state M1 (sigma B-frags), init I
  #pragma unroll
  for (int p = 0; p < 4; ++p) {
    int k0 = 8 * h + 2 * p;
    Blo.u[p] = ((sig(k0) == n)          ? 0x3F80u : 0u) |
               ((sig(k0 + 1) == n)      ? 0x3F800000u : 0u);
    Bhi.u[p] = ((sig(16 + k0) == n)     ? 0x3F80u : 0u) |
               ((sig(16 + k0 + 1) == n) ? 0x3F800000u : 0u);
  }
  float16 D2;                        // chain-2 pending N = M2^T (f32 C-layout), init I
  #pragma unroll
  for (int q = 0; q < 16; ++q)
    D2[q] = (((q & 3) + 8 * (q >> 2) + 4 * h) == n) ? 1.0f : 0.0f;

  int   Kacc  = 0;
  float numer = 0.0f;
  const float16 Zv = {0,0,0,0,0,0,0,0,0,0,0,0,0,0,0,0};

#define RESCALE16(DV) do {                                                   \
    float mx_ = fmaxf(fmaxf(fmaxf(DV[0], DV[1]), fmaxf(DV[2], DV[3])),       \
                      fmaxf(fmaxf(DV[4], DV[5]), fmaxf(DV[6], DV[7])));      \
    mx_ = fmaxf(mx_, fmaxf(fmaxf(fmaxf(DV[8], DV[9]),  fmaxf(DV[10], DV[11])),\
                           fmaxf(fmaxf(DV[12], DV[13]), fmaxf(DV[14], DV[15]))));\
    mx_ = fmaxf(mx_, __shfl_xor(mx_, 32));   /* column-0 max (valid bound) */\
    mx_ = __uint_as_float((unsigned)__builtin_amdgcn_readfirstlane(          \
              (int)__float_as_uint(mx_)));                                   \
    int E_ = (int)((__float_as_uint(mx_) >> 23) & 0xffu);                    \
    float sc_ = __uint_as_float((unsigned)(254 - E_) << 23);                 \
    Kacc += E_ - 127;                                                        \
    _Pragma("unroll")                                                        \
    for (int q_ = 0; q_ < 16; ++q_) DV[q_] *= sc_;                           \
  } while (0)

  // chain 1 (forward): B <- pack( rescale?( diag(g) * (A1 . B) ) )
#define FOLD1(JJ, RSC) do {                                                  \
    const float4* gw = (const float4*)(gp1 + (JJ) * 32);                     \
    float4 wa = gw[h], wb = gw[h + 2], wc = gw[h + 4], wd = gw[h + 6];       \
    float16 D = __builtin_amdgcn_mfma_f32_32x32x16_bf16(A1lo.s, Blo.s, Zv, 0, 0, 0); \
    D = __builtin_amdgcn_mfma_f32_32x32x16_bf16(A1hi.s, Bhi.s, D, 0, 0, 0);  \
    D[0]  *= wa.x; D[1]  *= wa.y; D[2]  *= wa.z; D[3]  *= wa.w;              \
    D[4]  *= wb.x; D[5]  *= wb.y; D[6]  *= wb.z; D[7]  *= wb.w;              \
    D[8]  *= wc.x; D[9]  *= wc.y; D[10] *= wc.z; D[11] *= wc.w;              \
    D[12] *= wd.x; D[13] *= wd.y; D[14] *= wd.z; D[15] *= wd.w;              \
    if (RSC) RESCALE16(D);                                                   \
    Blo.u[0] = cvtpk(D[0],  D[1]);  Blo.u[1] = cvtpk(D[2],  D[3]);           \
    Blo.u[2] = cvtpk(D[4],  D[5]);  Blo.u[3] = cvtpk(D[6],  D[7]);           \
    Bhi.u[0] = cvtpk(D[8],  D[9]);  Bhi.u[1] = cvtpk(D[10], D[11]);          \
    Bhi.u[2] = cvtpk(D[12], D[13]); Bhi.u[3] = cvtpk(D[14], D[15]);          \
  } while (0)

  // chain 2 (reverse): D2 <- A2 . pack( rescale?( diag(g) * D2 ) )
#define FOLD2(JJ, RSC) do {                                                  \
    const float4* gw = (const float4*)(gp2 + (JJ) * 32);                     \
    float4 wa = gw[h], wb = gw[h + 2], wc = gw[h + 4], wd = gw[h + 6];       \
    D2[0]  *= wa.x; D2[1]  *= wa.y; D2[2]  *= wa.z; D2[3]  *= wa.w;          \
    D2[4]  *= wb.x; D2[5]  *= wb.y; D2[6]  *= wb.z; D2[7]  *= wb.w;          \
    D2[8]  *= wc.x; D2[9]  *= wc.y; D2[10] *= wc.z; D2[11] *= wc.w;          \
    D2[12] *= wd.x; D2[13] *= wd.y; D2[14] *= wd.z; D2[15] *= wd.w;          \
    if (RSC) RESCALE16(D2);                                                  \
    Frag t2lo, t2hi;                                                         \
    t2lo.u[0] = cvtpk(D2[0],  D2[1]);  t2lo.u[1] = cvtpk(D2[2],  D2[3]);     \
    t2lo.u[2] = cvtpk(D2[4],  D2[5]);  t2lo.u[3] = cvtpk(D2[6],  D2[7]);     \
    t2hi.u[0] = cvtpk(D2[8],  D2[9]);  t2hi.u[1] = cvtpk(D2[10], D2[11]);    \
    t2hi.u[2] = cvtpk(D2[12], D2[13]); t2hi.u[3] = cvtpk(D2[14], D2[15]);    \
    float16 Dn_ = __builtin_amdgcn_mfma_f32_32x32x16_bf16(A2lo.s, t2lo.s, Zv, 0, 0, 0); \
    D2 = __builtin_amdgcn_mfma_f32_32x32x16_bf16(A2hi.s, t2hi.s, Dn_, 0, 0, 0); \
  } while (0)

  // prologue: async-stage first window of each chain
  if (nw > 0) {
    gload16(emb + (size_t)min(c0, S - 8) * T + 4 * l, w1);
    if (c1 > cm) gload16(emb + (size_t)max(c1 - 8, 0) * T + 4 * l, w2);
  }

  for (int i = 0; i < nw; ++i) {
    const int pp  = (i & 1) << 8;
    float* w1c = w1 + pp;
    float* w2c = w2 + pp;

    const int bf   = c0 + 8 * i;          // fwd window first step
    const int lb1  = min(bf, S - 8);      // fwd load base
    const int d1   = bf - lb1;
    const int hi1  = min(8, cm - bf);     // >= 1 for i < nw

    const int jhi  = c1 - 8 * i;          // rev window end (exclusive)
    const bool ron = (jhi > cm);
    const int lb2  = max(jhi - 8, 0);     // rev load base
    const int klo2 = max(cm - lb2, 0);
    const int khi2 = jhi - lb2;           // <= 8

    // wait both async loads, convert em -> g = 2^em in place (wave-private)
    asm volatile("s_waitcnt vmcnt(0)" ::: "memory");
    {
      float4 r = ((const float4*)w1c)[l];
      r.x = exp2f(r.x * L2E); r.y = exp2f(r.y * L2E);
      r.z = exp2f(r.z * L2E); r.w = exp2f(r.w * L2E);
      ((float4*)w1c)[l] = r;
    }
    if (ron) {
      float4 r = ((const float4*)w2c)[l];
      r.x = exp2f(r.x * L2E); r.y = exp2f(r.y * L2E);
      r.z = exp2f(r.z * L2E); r.w = exp2f(r.w * L2E);
      ((float4*)w2c)[l] = r;
    }

    // issue next windows' loads now; 16 folds below hide the latency
    if (i + 1 < nw) {
      const int npp = pp ^ 256;
      gload16(emb + (size_t)min(c0 + 8 * (i + 1), S - 8) * T + 4 * l, w1 + npp);
      const int njhi = c1 - 8 * (i + 1);
      if (njhi > cm)
        gload16(emb + (size_t)max(njhi - 8, 0) * T + 4 * l, w2 + npp);
    }

    const float* gp1 = w1c + d1 * 32;
    const float* gp2 = w2c;

    // applied masks (funnel over ballot words, range-clamped)
    unsigned eff1;
    {
      const int wdi = bf >> 6, o = bf & 63;
      unsigned long long bits = s_mb[wdi] >> o;
      if (o) bits |= s_mb[wdi + 1] << (64 - o);
      eff1 = (unsigned)(bits & 0xFFull) & (unsigned)((1u << hi1) - 1u);
    }
    unsigned eff2 = 0u;
    if (ron) {
      const int wdi = lb2 >> 6, o = lb2 & 63;
      unsigned long long bits = s_mb[wdi] >> o;
      if (o) bits |= s_mb[wdi + 1] << (64 - o);
      eff2 = (unsigned)(bits & 0xFFull) &
             (unsigned)((1u << khi2) - (1u << klo2));
    }

    // numerator: one lane per step (em recovered from f32 g).
    // NOTE the l < 8 clamp: HW masks 32-bit shifts to 5 bits, so without it
    // lanes 32..39 alias bits 0..7 and read far out of the window (R3 NaN).
    if (l < 8 && ((eff1 >> l) & 1u)) {
      int j = bf + l;
      int tg = (int)s_tags[j], tp = (int)s_tags[j - 1];
      numer += s_trans[tp * T + tg] + log2f(gp1[l * 32 + tg]) * LN2f;
    }
    if (l < 8 && ((eff2 >> l) & 1u)) {
      int j = lb2 + l;
      int tg = (int)s_tags[j], tp = (int)s_tags[j - 1];
      numer += s_trans[tp * T + tg] + log2f(gp2[l * 32 + tg]) * LN2f;
    }

    if (eff1 == 0xFFu && eff2 == 0xFFu) {
      // interleaved fast path: two independent chains feed both pipes
      FOLD1(0, false); FOLD2(7, false);
      FOLD1(1, false); FOLD2(6, false);
      FOLD1(2, false); FOLD2(5, false);
      FOLD1(3, false); FOLD2(4, false);
      FOLD1(4, false); FOLD2(3, false);
      FOLD1(5, false); FOLD2(2, false);
      FOLD1(6, false); FOLD2(1, false);
      FOLD1(7, true);  FOLD2(0, true);
    } else {
      if (eff1 == 0xFFu) {
        FOLD1(0, false); FOLD1(1, false); FOLD1(2, false); FOLD1(3, false);
        FOLD1(4, false); FOLD1(5, false); FOLD1(6, false); FOLD1(7, true);
      } else {
        for (int jj = 0; jj < hi1; ++jj)
          if ((eff1 >> jj) & 1u) FOLD1(jj, true);
      }
      if (eff2 == 0xFFu) {
        FOLD2(7, false); FOLD2(6, false); FOLD2(5, false); FOLD2(4, false);
        FOLD2(3, false); FOLD2(2, false); FOLD2(1, false); FOLD2(0, true);
      } else if (ron) {
        for (int jj = khi2 - 1; jj >= klo2; --jj)
          if ((eff2 >> jj) & 1u) FOLD2(jj, true);
      }
    }
  }
#undef FOLD1
#undef FOLD2

  // ---- finalize chain 2 (N = M2^T), combine C = M2*M1 via N-as-A trick ----
  RESCALE16(D2);
  {
    Frag Z2lo, Z2hi;
    Z2lo.u[0] = cvtpk(D2[0],  D2[1]);  Z2lo.u[1] = cvtpk(D2[2],  D2[3]);
    Z2lo.u[2] = cvtpk(D2[4],  D2[5]);  Z2lo.u[3] = cvtpk(D2[6],  D2[7]);
    Z2hi.u[0] = cvtpk(D2[8],  D2[9]);  Z2hi.u[1] = cvtpk(D2[10], D2[11]);
    Z2hi.u[2] = cvtpk(D2[12], D2[13]); Z2hi.u[3] = cvtpk(D2[14], D2[15]);
    float16 Dc = __builtin_amdgcn_mfma_f32_32x32x16_bf16(Z2lo.s, Blo.s, Zv, 0, 0, 0);
    Dc = __builtin_amdgcn_mfma_f32_32x32x16_bf16(Z2hi.s, Bhi.s, Dc, 0, 0, 0);
    RESCALE16(Dc);
    Blo.u[0] = cvtpk(Dc[0],  Dc[1]);  Blo.u[1] = cvtpk(Dc[2],  Dc[3]);
    Blo.u[2] = cvtpk(Dc[4],  Dc[5]);  Blo.u[3] = cvtpk(Dc[6],  Dc[7]);
    Bhi.u[0] = cvtpk(Dc[8],  Dc[9]);  Bhi.u[1] = cvtpk(Dc[10], Dc[11]);
    Bhi.u[2] = cvtpk(Dc[12], Dc[13]); Bhi.u[3] = cvtpk(Dc[14], Dc[15]);
  }
#undef RESCALE16

  // ---- publish chunk matrix (packed bf16 row pairs, sigma-unscrambled) ----
  {
    unsigned* mw = s_mats + wv * 544;
    #pragma unroll
    for (int p = 0; p < 4; ++p) {
      mw[(sig(8 * h + 2 * p)      >> 1) * 34 + n] = Blo.u[p];
      mw[(sig(16 + 8 * h + 2 * p) >> 1) * 34 + n] = Bhi.u[p];
    }
  }
  #pragma unroll
  for (int d = 1; d < 64; d <<= 1) numer += __shfl_xor(numer, d);
  if (l == 0) { s_num[wv] = numer; s_K[wv] = Kacc; }
  __syncthreads();

  // ---- phase 2: wave 0 scans the 8 chunk matrices ----
  if (wv == 0) {
    const int t = n;
    const float em0 = emb[head * T + t];
    float sc0 = (startT[t] + em0) * L2E;
    float m0 = sc0;
    #pragma unroll
    for (int d = 1; d < 32; d <<= 1) m0 = fmaxf(m0, __shfl_xor(m0, d));
    float e = exp2f(sc0 - m0);
    float Mtot = m0;

    const unsigned sh = (t & 1) ? 0u : 16u;   // select row-half of packed word
    for (int c = 0; c < 8; ++c) {
      const unsigned* mw = s_mats + c * 544 + (t >> 1) * 34;
      float acc = 0.0f;
      #pragma unroll
      for (int q2 = 0; q2 < 16; ++q2) {
        uint2 w2 = *(const uint2*)(mw + 2 * q2);
        float vlo = __uint_as_float((w2.x << sh) & 0xFFFF0000u);
        float vhi = __uint_as_float((w2.y << sh) & 0xFFFF0000u);
        acc = fmaf(vlo, bcast_lane(e, 2 * q2), acc);
        acc = fmaf(vhi, bcast_lane(e, 2 * q2 + 1), acc);
      }
      e = acc;
      Mtot += (float)s_K[c];
      float mx = e;
      #pragma unroll
      for (int d = 1; d < 32; d <<= 1) mx = fmaxf(mx, __shfl_xor(mx, d));
      int E = (int)((__float_as_uint(mx) >> 23) & 0xffu);
      e *= __uint_as_float((unsigned)(254 - E) << 23);
      Mtot += (float)(E - 127);
    }

    float fv = e * exp2f(endT[t] * L2E);
    #pragma unroll
    for (int d = 1; d < 32; d <<= 1) fv += __shfl_xor(fv, d);
    float denom = (Mtot + log2f(fv)) * LN2f;

    if (l == 0) {
      if (cnt > 0) {
        float ntot = 0.0f;
        for (int wq = 0; wq < 8; ++wq) ntot += s_num[wq];
        int th = (int)s_tags[head], tt = (int)s_tags[tail];
        ntot += startT[th] + bcast_lane(em0, th) + endT[tt];
        atomicAdd(&ws[0], (denom - ntot) / ((float)cnt + 1e-6f));
        atomicAdd(&ws[1], 1.0f);
      }
      __threadfence();
      unsigned done = atomicAdd((unsigned*)ws + 2, 1u);
      if (done == (unsigned)(B - 1)) {
        __threadfence();
        out[0] = ws[0] / (ws[1] + 1e-6f);
      }
    }
  }
}

extern "C" void kernel_launch(void* const* d_in, const int* in_sizes, int n_in,
                              void* d_out, int out_size, void* d_ws, size_t ws_size,
                              hipStream_t stream) {
  const float* em     = (const float*)d_in[0];
  const int*   tags   = (const int*)d_in[1];
  const int*   mask   = (const int*)d_in[2];
  const float* startT = (const float*)d_in[3];
  const float* trans  = (const float*)d_in[4];
  const float* endT   = (const float*)d_in[5];
  float* out = (float*)d_out;
  float* ws  = (float*)d_ws;

  const int B = in_sizes[0] / (S * T);

  crf_zero<<<1, 1, 0, stream>>>(ws);
  crf_main<<<B, 512, 0, stream>>>(em, tags, mask, startT, trans, endT, ws, out, B);
}

// Round 5
// 261.850 us; speedup vs baseline: 1.0391x; 1.0391x over previous
//
#include <hip/hip_runtime.h>
#include <cstdint>

static constexpr int S = 1024;
static constexpr int T = 32;
static constexpr float L2E  = 1.4426950408889634f;  // log2(e)
static constexpr float LN2f = 0.6931471805599453f;  // ln(2)

typedef __attribute__((ext_vector_type(8)))  short  short8;
typedef __attribute__((ext_vector_type(16))) float  float16;

union Frag { unsigned u[4]; short8 s; };

__global__ void crf_zero(float* ws) {
  ws[0] = 0.0f; ws[1] = 0.0f; ((unsigned*)ws)[2] = 0u;
}

__device__ __forceinline__ float bcast_lane(float v, int k) {
  return __uint_as_float((unsigned)__builtin_amdgcn_readlane((int)__float_as_uint(v), k));
}

// single-instruction rounded pack: two f32 -> bf16x2 (lo = first arg).
__device__ __forceinline__ unsigned cvtpk(float lo, float hi) {
  unsigned r;
  asm("v_cvt_pk_bf16_f32 %0, %1, %2" : "=v"(r) : "v"(lo), "v"(hi));
  return r;
}

// async global->LDS, 16 B per lane: dest = wave-uniform base + lane*16.
__device__ __forceinline__ void gload16(const float* src, float* dst) {
  __builtin_amdgcn_global_load_lds(
      (const __attribute__((address_space(1))) unsigned int*)(src),
      (__attribute__((address_space(3))) unsigned int*)(dst),
      16, 0, 0);
}

// sigma: fixed row permutation mapping MFMA C-layout row slots onto B-operand
// row slots (swaps 4-blocks 1<->2 within each 16). With A pre-permuted
// (A'[m][k] = X[m][sig(k)]) the product is exact and D's packed pairs ARE the
// next B-operand - no lane data movement.
__device__ __forceinline__ int sig(int k) {
  int g2 = (k >> 2) & 3;
  if (g2 == 1) g2 = 2; else if (g2 == 2) g2 = 1;
  return (k & ~12) | (g2 << 2);
}

// Block = one batch (512 thr = 8 waves). Active range (head, tail] split into
// 8 equal chunks; wave w folds its chunk into a 32x32 matrix via MFMA in the
// linear 2^x domain (M <- diag(g_j) P^T M). em staged async via
// global_load_lds into wave-private double-buffered 8-step windows.
// KEY (R5): the g-window pool and the chunk-matrix pool are temporally
// disjoint -> overlaid in one LDS union, cutting LDS 40.4 -> ~24 KB so
// 4 blocks/CU (32-wave cap) fit: 2x the dependency-chains in flight per SIMD
// vs every previous config (the measured invariant limiter).
__global__ __launch_bounds__(512, 8) void crf_main(
    const float* __restrict__ em, const int* __restrict__ tags,
    const int* __restrict__ mask, const float* __restrict__ startT,
    const float* __restrict__ trans, const float* __restrict__ endT,
    float* __restrict__ ws, float* __restrict__ out, int B)
{
  // 17408 B pool: fold phase = 8 waves x 512 f32 g-windows (16384 B);
  // publish/scan phase = 8 chunk mats x 544 u32 (17408 B). Barrier-separated.
  __shared__ __align__(16) unsigned s_pool[8 * 544];
  __shared__ float s_trans[1024];                      // 4 KiB
  __shared__ short s_tags[1024];                       // 2 KiB
  __shared__ unsigned long long s_mb[17];
  __shared__ int   s_head, s_tail, s_cnt, s_K[8];
  __shared__ float s_num[8];

  const int tid = threadIdx.x;
  const int l   = tid & 63;
  const int wv  = tid >> 6;
  const int b   = blockIdx.x;
  const int n   = l & 31;        // MFMA column / tag index
  const int h   = l >> 5;        // lane half

  const float* emb   = em   + (size_t)b * S * T;
  const int*   maskb = mask + (size_t)b * S;
  const int*   tagsb = tags + (size_t)b * S;

  // ---- cooperative staging: tags, trans, mask ballots ----
  for (int i = tid; i < 1024; i += 512) {
    s_tags[i]  = (short)tagsb[i];
    s_trans[i] = trans[i];
  }
  {
    unsigned long long b0 = __ballot(maskb[wv * 128 + l] != 0);
    unsigned long long b1 = __ballot(maskb[wv * 128 + 64 + l] != 0);
    if (l == 0) { s_mb[2 * wv] = b0; s_mb[2 * wv + 1] = b1; }
    if (tid == 0) s_mb[16] = 0ull;
  }

  // ---- A' = sigma-permuted P^T as bf16 frags (lane: m=n, k-slot=8h+2p+par) ----
  Frag Alo, Ahi;
  #pragma unroll
  for (int p = 0; p < 4; ++p) {
    int k0 = 8 * h + 2 * p;
    Alo.u[p] = cvtpk(exp2f(trans[sig(k0 + 0)      * T + n] * L2E),
                     exp2f(trans[sig(k0 + 1)      * T + n] * L2E));
    Ahi.u[p] = cvtpk(exp2f(trans[sig(16 + k0 + 0) * T + n] * L2E),
                     exp2f(trans[sig(16 + k0 + 1) * T + n] * L2E));
  }
  __syncthreads();

  if (wv == 0) {
    int first = 0x7fffffff, last = -1, pc = 0;
    if (l < 16) {
      unsigned long long w = s_mb[l];
      if (w) {
        first = 64 * l + (int)__builtin_ctzll(w);
        last  = 64 * l + 63 - (int)__builtin_clzll(w);
        pc    = (int)__builtin_popcountll(w);
      }
    }
    #pragma unroll
    for (int d = 1; d < 64; d <<= 1) {
      first = min(first, __shfl_xor(first, d));
      last  = max(last,  __shfl_xor(last,  d));
      pc   += __shfl_xor(pc, d);
    }
    if (l == 0) { s_head = first; s_tail = last; s_cnt = pc; }
  }
  __syncthreads();
  const int cnt  = s_cnt;
  const int head = (cnt > 0) ? s_head : 0;
  const int tail = (cnt > 0) ? s_tail : 0;

  // ---- equal-split chunk for this wave ----
  const int span = tail - head;
  const int Lc   = (span + 7) >> 3;
  const int c0   = head + 1 + wv * Lc;
  const int c1   = min(c0 + Lc, tail + 1);

  float* bcur = (float*)s_pool + wv * 512;   // ping-pong 8-step windows (wave-private)
  float* bnxt = bcur + 256;

  Frag Blo, Bhi;                    // running M in sigma-storage, init = I
  #pragma unroll
  for (int p = 0; p < 4; ++p) {
    int k0 = 8 * h + 2 * p;
    Blo.u[p] = ((sig(k0) == n)          ? 0x3F80u : 0u) |
               ((sig(k0 + 1) == n)      ? 0x3F800000u : 0u);
    Bhi.u[p] = ((sig(16 + k0) == n)     ? 0x3F80u : 0u) |
               ((sig(16 + k0 + 1) == n) ? 0x3F800000u : 0u);
  }
  int   Kacc  = 0;
  float numer = 0.0f;
  const float16 Zv = {0,0,0,0,0,0,0,0,0,0,0,0,0,0,0,0};

#define FOLD(JJ, RSC) do {                                                   \
    const float4* gw = (const float4*)(gp + (JJ) * 32);                      \
    float4 wa = gw[h], wb = gw[h + 2], wc = gw[h + 4], wd = gw[h + 6];       \
    float16 D = __builtin_amdgcn_mfma_f32_32x32x16_bf16(Alo.s, Blo.s, Zv, 0, 0, 0); \
    D = __builtin_amdgcn_mfma_f32_32x32x16_bf16(Ahi.s, Bhi.s, D, 0, 0, 0);   \
    D[0]  *= wa.x; D[1]  *= wa.y; D[2]  *= wa.z; D[3]  *= wa.w;              \
    D[4]  *= wb.x; D[5]  *= wb.y; D[6]  *= wb.z; D[7]  *= wb.w;              \
    D[8]  *= wc.x; D[9]  *= wc.y; D[10] *= wc.z; D[11] *= wc.w;              \
    D[12] *= wd.x; D[13] *= wd.y; D[14] *= wd.z; D[15] *= wd.w;              \
    if (RSC) {                                                               \
      float mx = fmaxf(fmaxf(fmaxf(D[0], D[1]), fmaxf(D[2], D[3])),          \
                       fmaxf(fmaxf(D[4], D[5]), fmaxf(D[6], D[7])));         \
      mx = fmaxf(mx, fmaxf(fmaxf(fmaxf(D[8], D[9]),  fmaxf(D[10], D[11])),   \
                           fmaxf(fmaxf(D[12], D[13]), fmaxf(D[14], D[15]))));\
      mx = fmaxf(mx, __shfl_xor(mx, 32));   /* column-0 max (valid bound) */ \
      mx = __uint_as_float((unsigned)__builtin_amdgcn_readfirstlane(         \
               (int)__float_as_uint(mx)));                                   \
      int E = (int)((__float_as_uint(mx) >> 23) & 0xffu);                    \
      float sc = __uint_as_float((unsigned)(254 - E) << 23);                 \
      Kacc += E - 127;                                                       \
      _Pragma("unroll")                                                      \
      for (int q_ = 0; q_ < 16; ++q_) D[q_] *= sc;                           \
    }                                                                        \
    Blo.u[0] = cvtpk(D[0],  D[1]);  Blo.u[1] = cvtpk(D[2],  D[3]);           \
    Blo.u[2] = cvtpk(D[4],  D[5]);  Blo.u[3] = cvtpk(D[6],  D[7]);           \
    Bhi.u[0] = cvtpk(D[8],  D[9]);  Bhi.u[1] = cvtpk(D[10], D[11]);          \
    Bhi.u[2] = cvtpk(D[12], D[13]); Bhi.u[3] = cvtpk(D[14], D[15]);          \
  } while (0)

  // prologue: async-stage first 8-step window
  if (c0 < c1) {
    const int base = min(c0, S - 8);
    gload16(emb + (size_t)base * T + 4 * l, bcur);
  }

  for (int j0 = c0; j0 < c1; j0 += 8) {
    const int ns   = min(8, c1 - j0);
    const int base = min(j0, S - 8);
    const int d    = j0 - base;          // shift of j0 within loaded window

    // wait this wave's async load, then convert em -> g = 2^em in place
    // (each lane converts exactly the 16 B it loaded; wave-private buffer)
    asm volatile("s_waitcnt vmcnt(0)" ::: "memory");
    {
      float4 r = ((const float4*)bcur)[l];
      r.x = exp2f(r.x * L2E); r.y = exp2f(r.y * L2E);
      r.z = exp2f(r.z * L2E); r.w = exp2f(r.w * L2E);
      ((float4*)bcur)[l] = r;
    }

    // issue next window's async load now; folds below hide its latency
    if (j0 + 8 < c1) {
      const int nb = min(j0 + 8, S - 8);
      gload16(emb + (size_t)nb * T + 4 * l, bnxt);
    }

    const float* gp = bcur + d * 32;

    // 8-bit applied-mask at arbitrary offset j0 (funnel over ballot words)
    const int w = j0 >> 6, o = j0 & 63;
    unsigned long long bits = s_mb[w] >> o;
    if (o) bits |= s_mb[w + 1] << (64 - o);
    unsigned eff = (unsigned)(bits & 0xFFull) & (unsigned)((1u << ns) - 1u);

    // numerator: lanes 0..ns-1 take one step each (em recovered from f32 g)
    if (l < ns && ((eff >> l) & 1u)) {
      int j  = j0 + l;
      int tg = (int)s_tags[j], tp = (int)s_tags[j - 1];
      float gval = gp[l * 32 + tg];
      numer += s_trans[tp * T + tg] + log2f(gval) * LN2f;
    }

    if (eff == 0xFFu) {
      #pragma unroll
      for (int jj = 0; jj < 8; ++jj) FOLD(jj, (jj == 7));
    } else {
      for (int jj = 0; jj < ns; ++jj)
        if ((eff >> jj) & 1u) FOLD(jj, true);
    }

    float* tmp = bcur; bcur = bnxt; bnxt = tmp;
  }
#undef FOLD

  // ---- all folds done before the mats overlay is written (union hazard) ----
  __syncthreads();

  // ---- publish chunk matrix (packed bf16 row pairs, sigma-unscrambled) ----
  {
    unsigned* mw = s_pool + wv * 544;
    #pragma unroll
    for (int p = 0; p < 4; ++p) {
      mw[(sig(8 * h + 2 * p)      >> 1) * 34 + n] = Blo.u[p];
      mw[(sig(16 + 8 * h + 2 * p) >> 1) * 34 + n] = Bhi.u[p];
    }
  }
  #pragma unroll
  for (int d = 1; d < 64; d <<= 1) numer += __shfl_xor(numer, d);
  if (l == 0) { s_num[wv] = numer; s_K[wv] = Kacc; }
  __syncthreads();

  // ---- phase 2: wave 0 scans the 8 chunk matrices ----
  if (wv == 0) {
    const int t = n;
    const float em0 = emb[head * T + t];
    float sc0 = (startT[t] + em0) * L2E;
    float m0 = sc0;
    #pragma unroll
    for (int d = 1; d < 32; d <<= 1) m0 = fmaxf(m0, __shfl_xor(m0, d));
    float e = exp2f(sc0 - m0);
    float Mtot = m0;

    const unsigned sh = (t & 1) ? 0u : 16u;   // select row-half of packed word
    for (int c = 0; c < 8; ++c) {
      const unsigned* mw = s_pool + c * 544 + (t >> 1) * 34;
      float acc = 0.0f;
      #pragma unroll
      for (int q2 = 0; q2 < 16; ++q2) {
        uint2 w2 = *(const uint2*)(mw + 2 * q2);
        float vlo = __uint_as_float((w2.x << sh) & 0xFFFF0000u);
        float vhi = __uint_as_float((w2.y << sh) & 0xFFFF0000u);
        acc = fmaf(vlo, bcast_lane(e, 2 * q2), acc);
        acc = fmaf(vhi, bcast_lane(e, 2 * q2 + 1), acc);
      }
      e = acc;
      Mtot += (float)s_K[c];
      float mx = e;
      #pragma unroll
      for (int d = 1; d < 32; d <<= 1) mx = fmaxf(mx, __shfl_xor(mx, d));
      int E = (int)((__float_as_uint(mx) >> 23) & 0xffu);
      e *= __uint_as_float((unsigned)(254 - E) << 23);
      Mtot += (float)(E - 127);
    }

    float fv = e * exp2f(endT[t] * L2E);
    #pragma unroll
    for (int d = 1; d < 32; d <<= 1) fv += __shfl_xor(fv, d);
    float denom = (Mtot + log2f(fv)) * LN2f;

    if (l == 0) {
      if (cnt > 0) {
        float ntot = 0.0f;
        for (int wq = 0; wq < 8; ++wq) ntot += s_num[wq];
        int th = (int)s_tags[head], tt = (int)s_tags[tail];
        ntot += startT[th] + bcast_lane(em0, th) + endT[tt];
        atomicAdd(&ws[0], (denom - ntot) / ((float)cnt + 1e-6f));
        atomicAdd(&ws[1], 1.0f);
      }
      __threadfence();
      unsigned done = atomicAdd((unsigned*)ws + 2, 1u);
      if (done == (unsigned)(B - 1)) {
        __threadfence();
        out[0] = ws[0] / (ws[1] + 1e-6f);
      }
    }
  }
}

extern "C" void kernel_launch(void* const* d_in, const int* in_sizes, int n_in,
                              void* d_out, int out_size, void* d_ws, size_t ws_size,
                              hipStream_t stream) {
  const float* em     = (const float*)d_in[0];
  const int*   tags   = (const int*)d_in[1];
  const int*   mask   = (const int*)d_in[2];
  const float* startT = (const float*)d_in[3];
  const float* trans  = (const float*)d_in[4];
  const float* endT   = (const float*)d_in[5];
  float* out = (float*)d_out;
  float* ws  = (float*)d_ws;

  const int B = in_sizes[0] / (S * T);

  crf_zero<<<1, 1, 0, stream>>>(ws);
  crf_main<<<B, 512, 0, stream>>>(em, tags, mask, startT, trans, endT, ws, out, B);
}